// Round 1
// baseline (357.650 us; speedup 1.0000x reference)
//
#include <hip/hip_runtime.h>
#include <math.h>

typedef unsigned short u16;
typedef unsigned int   u32;
typedef __attribute__((ext_vector_type(8))) short bf16x8;
typedef __attribute__((ext_vector_type(4))) float floatx4;

// B=2, S=2048, D=1024, H=16, Dh=64, M=B*S=4096
#define SEQ 2048
#define DM  1024
#define NH  16
#define DH  64
#define MM  4096

__device__ __forceinline__ u16 f2bf(float f) {
    u32 u = __builtin_bit_cast(u32, f);
    u += 0x7fffu + ((u >> 16) & 1u);
    return (u16)(u >> 16);
}

// ---------------- fp32 -> bf16 convert ----------------
__global__ void cvt_kernel(const float* __restrict__ src, u16* __restrict__ dst, int n4) {
    int i = blockIdx.x * 256 + threadIdx.x;
    if (i >= n4) return;
    float4 f = ((const float4*)src)[i];
    uint2 o;
    o.x = (u32)f2bf(f.x) | ((u32)f2bf(f.y) << 16);
    o.y = (u32)f2bf(f.z) | ((u32)f2bf(f.w) << 16);
    ((uint2*)dst)[i] = o;
}

// ---------------- NT GEMM: C[M,1024] = A[M,1024] * W[1024,1024]^T ----------------
// 64x64 block tile, 4 waves in 2x2, each wave 32x32 (2x2 MFMA tiles), BK=64.
// ropeMask bit z: apply RoPE to output of gridDim.z slice z.
template<bool OUTF32>
__global__ __launch_bounds__(256) void gemm64(const u16* __restrict__ Abf,
                                              const u16* __restrict__ Wbase,
                                              u16* __restrict__ outbf,
                                              float* __restrict__ outf,
                                              const int* __restrict__ pos,
                                              int ropeMask) {
    const int z  = blockIdx.z;
    const u16* Wp = Wbase + (size_t)z * (DM * DM);
    const int n0 = blockIdx.x * 64, m0 = blockIdx.y * 64;
    const int tid  = threadIdx.x;
    const int lane = tid & 63, w = tid >> 6;
    const int lm = lane & 15, quad = lane >> 4;
    const int wr = w >> 1, wc = w & 1;

    __shared__ __align__(16) u16 lsA[64 * 72];
    __shared__ __align__(16) u16 lsB[64 * 72];

    floatx4 acc[2][2];
    const floatx4 z4 = {0.f, 0.f, 0.f, 0.f};
    acc[0][0] = z4; acc[0][1] = z4; acc[1][0] = z4; acc[1][1] = z4;

    for (int k0 = 0; k0 < DM; k0 += 64) {
#pragma unroll
        for (int rep = 0; rep < 2; ++rep) {
            int gg = tid + rep * 256;
            int row = gg >> 3, cs = gg & 7;
            *(uint4*)&lsA[row * 72 + cs * 8] =
                *(const uint4*)&Abf[(size_t)(m0 + row) * DM + k0 + cs * 8];
            *(uint4*)&lsB[row * 72 + cs * 8] =
                *(const uint4*)&Wp[(size_t)(n0 + row) * DM + k0 + cs * 8];
        }
        __syncthreads();
#pragma unroll
        for (int kk = 0; kk < 64; kk += 32) {
            const int ko = kk + quad * 8;
            bf16x8 a0 = *(const bf16x8*)&lsA[(wr * 32 + lm) * 72 + ko];
            bf16x8 a1 = *(const bf16x8*)&lsA[(wr * 32 + 16 + lm) * 72 + ko];
            bf16x8 b0 = *(const bf16x8*)&lsB[(wc * 32 + lm) * 72 + ko];
            bf16x8 b1 = *(const bf16x8*)&lsB[(wc * 32 + 16 + lm) * 72 + ko];
            acc[0][0] = __builtin_amdgcn_mfma_f32_16x16x32_bf16(a0, b0, acc[0][0], 0, 0, 0);
            acc[0][1] = __builtin_amdgcn_mfma_f32_16x16x32_bf16(a0, b1, acc[0][1], 0, 0, 0);
            acc[1][0] = __builtin_amdgcn_mfma_f32_16x16x32_bf16(a1, b0, acc[1][0], 0, 0, 0);
            acc[1][1] = __builtin_amdgcn_mfma_f32_16x16x32_bf16(a1, b1, acc[1][1], 0, 0, 0);
        }
        __syncthreads();
    }

    const bool rope = ((ropeMask >> z) & 1) != 0;
#pragma unroll
    for (int mt = 0; mt < 2; ++mt)
#pragma unroll
        for (int nt = 0; nt < 2; ++nt)
#pragma unroll
            for (int r = 0; r < 4; ++r) {
                int row = m0 + wr * 32 + mt * 16 + quad * 4 + r;
                int col = n0 + wc * 32 + nt * 16 + lm;
                float v  = acc[mt][nt][r];
                float pv = __shfl_xor(v, 1);   // partner column (col ^ 1), same row
                if (rope) {
                    int d  = col & (DH - 1);
                    int i2 = (d >> 1) * 2;
                    float p = (float)pos[row & (SEQ - 1)];
                    // theta^(-2i/64) = exp(-2i * ln(10000)/64)
                    float freq = __expf(-(float)i2 * (9.2103403719761836f / 64.0f));
                    float sv, cv;
                    sincosf(p * freq, &sv, &cv);
                    v = (col & 1) ? fmaf(pv, sv, v * cv) : fmaf(v, cv, -pv * sv);
                }
                if (OUTF32)
                    outf[(size_t)row * DM + col] = v;
                else
                    outbf[(size_t)z * (MM * DM) + (size_t)row * DM + col] = f2bf(v);
            }
}

// ---------------- causal flash attention ----------------
// grid: (S/64 q-tiles, B*H). block: 256 threads = 4 waves, wave w owns q rows [w*16, w*16+16).
__global__ __launch_bounds__(256) void attn_kernel(const u16* __restrict__ Q,
                                                   const u16* __restrict__ K,
                                                   const u16* __restrict__ V,
                                                   u16* __restrict__ AO) {
    const int bx = blockIdx.x;                    // q tile index
    const int b  = blockIdx.y >> 4, h = blockIdx.y & 15;
    const int q0 = bx * 64;
    const int tid = threadIdx.x, w = tid >> 6, lane = tid & 63;
    const int lm = lane & 15, quad = lane >> 4;

    __shared__ __align__(16) u16 lsK[64 * 72];    // [key][dim]
    __shared__ __align__(16) u16 lsV[64 * 72];    // [dim][key]  (transposed)
    __shared__ __align__(16) u16 lsP[4][16 * 72]; // per-wave P tile [qrow][key]

    // Q fragments (A-operand, loaded once): row = q0+w*16+lm, k = ks*32+quad*8..+8
    const size_t qbase = ((size_t)(b * SEQ + q0 + w * 16 + lm)) * DM + h * DH;
    bf16x8 qa0 = *(const bf16x8*)&Q[qbase + quad * 8];
    bf16x8 qa1 = *(const bf16x8*)&Q[qbase + 32 + quad * 8];

    const floatx4 z4 = {0.f, 0.f, 0.f, 0.f};
    floatx4 o[4];
    float mi[4], li[4];
#pragma unroll
    for (int ct = 0; ct < 4; ++ct) o[ct] = z4;
#pragma unroll
    for (int r = 0; r < 4; ++r) { mi[r] = -INFINITY; li[r] = 0.f; }

    for (int kt = 0; kt <= bx; ++kt) {
        // stage K tile (natural) and V tile (transposed)
#pragma unroll
        for (int rep = 0; rep < 2; ++rep) {
            int gg = tid + rep * 256;
            int row = gg >> 3, cs = gg & 7;
            size_t gofs = ((size_t)(b * SEQ + kt * 64 + row)) * DM + h * DH + cs * 8;
            *(uint4*)&lsK[row * 72 + cs * 8] = *(const uint4*)&K[gofs];
            union { uint4 u; u16 s[8]; } vv;
            vv.u = *(const uint4*)&V[gofs];
#pragma unroll
            for (int j = 0; j < 8; ++j) lsV[(cs * 8 + j) * 72 + row] = vv.s[j];
        }
        __syncthreads();

        // S = Q K^T  (per wave: 16 q-rows x 64 keys)
        floatx4 s4[4];
#pragma unroll
        for (int ct = 0; ct < 4; ++ct) s4[ct] = z4;
#pragma unroll
        for (int ks = 0; ks < 2; ++ks) {
            bf16x8 a = ks ? qa1 : qa0;
#pragma unroll
            for (int ct = 0; ct < 4; ++ct) {
                bf16x8 bb = *(const bf16x8*)&lsK[(ct * 16 + lm) * 72 + ks * 32 + quad * 8];
                s4[ct] = __builtin_amdgcn_mfma_f32_16x16x32_bf16(a, bb, s4[ct], 0, 0, 0);
            }
        }

        // scale + causal mask (diagonal tile only; kt*64 == q0 there)
        float sc[4][4];
        const bool diag = (kt == bx);
#pragma unroll
        for (int ct = 0; ct < 4; ++ct)
#pragma unroll
            for (int r = 0; r < 4; ++r) {
                float v = s4[ct][r] * 0.125f;
                if (diag) {
                    int key = ct * 16 + lm;
                    int qr  = w * 16 + quad * 4 + r;
                    if (key > qr) v = -INFINITY;
                }
                sc[ct][r] = v;
            }

        // online softmax (rows live across the 16 lanes of a quad group)
        float mnew[4], alpha[4];
#pragma unroll
        for (int r = 0; r < 4; ++r) {
            float mx = fmaxf(fmaxf(sc[0][r], sc[1][r]), fmaxf(sc[2][r], sc[3][r]));
#pragma unroll
            for (int off = 1; off < 16; off <<= 1) mx = fmaxf(mx, __shfl_xor(mx, off));
            float mn = fmaxf(mi[r], mx);
            mnew[r]  = mn;
            alpha[r] = __expf(mi[r] - mn);
            float s = 0.f;
#pragma unroll
            for (int ct = 0; ct < 4; ++ct) {
                float p = __expf(sc[ct][r] - mn);
                sc[ct][r] = p;
                s += p;
            }
#pragma unroll
            for (int off = 1; off < 16; off <<= 1) s += __shfl_xor(s, off);
            li[r] = li[r] * alpha[r] + s;
            mi[r] = mn;
        }

        // rescale O, spill P (C-layout) to LDS as bf16 (becomes A-layout source)
#pragma unroll
        for (int ct = 0; ct < 4; ++ct)
#pragma unroll
            for (int r = 0; r < 4; ++r) {
                o[ct][r] *= alpha[r];
                lsP[w][(quad * 4 + r) * 72 + ct * 16 + lm] = f2bf(sc[ct][r]);
            }

        // O += P * V
#pragma unroll
        for (int ks = 0; ks < 2; ++ks) {
            bf16x8 ap = *(const bf16x8*)&lsP[w][lm * 72 + ks * 32 + quad * 8];
#pragma unroll
            for (int ct = 0; ct < 4; ++ct) {
                bf16x8 bv = *(const bf16x8*)&lsV[(ct * 16 + lm) * 72 + ks * 32 + quad * 8];
                o[ct] = __builtin_amdgcn_mfma_f32_16x16x32_bf16(ap, bv, o[ct], 0, 0, 0);
            }
        }
        __syncthreads();
    }

    // epilogue: O /= l, store bf16 in natural [b,s,h*64+d] layout
#pragma unroll
    for (int ct = 0; ct < 4; ++ct)
#pragma unroll
        for (int r = 0; r < 4; ++r) {
            float v = o[ct][r] / li[r];
            AO[((size_t)(b * SEQ + q0 + w * 16 + quad * 4 + r)) * DM + h * DH + ct * 16 + lm] =
                f2bf(v);
        }
}

extern "C" void kernel_launch(void* const* d_in, const int* in_sizes, int n_in,
                              void* d_out, int out_size, void* d_ws, size_t ws_size,
                              hipStream_t stream) {
    const float* x   = (const float*)d_in[0];
    const int*   pos = (const int*)d_in[1];
    const float* Wsrc[4] = {(const float*)d_in[2], (const float*)d_in[3],
                            (const float*)d_in[4], (const float*)d_in[5]};
    float* out = (float*)d_out;

    u16* ws = (u16*)d_ws;
    const size_t MD = (size_t)MM * DM;   // 4Mi elements
    const size_t DD = (size_t)DM * DM;   // 1Mi elements
    u16* Xbf = ws;                        // [4096,1024]
    u16* Wbf = ws + MD;                   // 4 weights contiguous (q,k,v,o)
    u16* Qbf = ws + MD + 4 * DD;          // Q, K, V contiguous, each MD
    u16* Kbf = Qbf + MD;
    u16* Vbf = Kbf + MD;
    u16* AObf = Xbf;                      // reuse: x dead after projections

    // converts
    cvt_kernel<<<(int)(MD / 4 / 256), 256, 0, stream>>>(x, Xbf, (int)(MD / 4));
    for (int i = 0; i < 4; ++i)
        cvt_kernel<<<(int)(DD / 4 / 256), 256, 0, stream>>>(Wsrc[i], Wbf + i * DD, (int)(DD / 4));

    // Q/K/V projections + fused RoPE on Q,K (z = 0,1,2)
    gemm64<false><<<dim3(16, 64, 3), 256, 0, stream>>>(Xbf, Wbf, Qbf, nullptr, pos, 0x3);

    // causal flash attention
    attn_kernel<<<dim3(SEQ / 64, 2 * NH), 256, 0, stream>>>(Qbf, Kbf, Vbf, AObf);

    // output projection -> fp32 d_out
    gemm64<true><<<dim3(16, 64, 1), 256, 0, stream>>>(AObf, Wbf + 3 * DD, nullptr, out, nullptr, 0);
}

// Round 2
// 314.267 us; speedup vs baseline: 1.1380x; 1.1380x over previous
//
#include <hip/hip_runtime.h>
#include <math.h>

typedef unsigned short u16;
typedef unsigned int   u32;
typedef __attribute__((ext_vector_type(8))) short bf16x8;
typedef __attribute__((ext_vector_type(4))) float floatx4;

// B=2, S=2048, D=1024, H=16, Dh=64, M=B*S=4096
#define SEQ 2048
#define DM  1024
#define NH  16
#define DH  64
#define MM  4096

__device__ __forceinline__ u16 f2bf(float f) {
    u32 u = __builtin_bit_cast(u32, f);
    u += 0x7fffu + ((u >> 16) & 1u);
    return (u16)(u >> 16);
}

__device__ __forceinline__ void async16(const u16* g, u16* l) {
    __builtin_amdgcn_global_load_lds(
        (const __attribute__((address_space(1))) void*)g,
        (__attribute__((address_space(3))) void*)l, 16, 0, 0);
}

// ---------------- fp32 -> bf16 convert ----------------
__global__ void cvt_kernel(const float* __restrict__ src, u16* __restrict__ dst, int n4) {
    int i = blockIdx.x * 256 + threadIdx.x;
    if (i >= n4) return;
    float4 f = ((const float4*)src)[i];
    uint2 o;
    o.x = (u32)f2bf(f.x) | ((u32)f2bf(f.y) << 16);
    o.y = (u32)f2bf(f.z) | ((u32)f2bf(f.w) << 16);
    ((uint2*)dst)[i] = o;
}

// ---------------- V transpose: V[b,s,h*64+d] -> Vt[(b*16+h)*64+d][s] ----------------
__global__ __launch_bounds__(256) void transpose_v(const u16* __restrict__ V, u16* __restrict__ Vt) {
    const int s0 = blockIdx.x * 64;
    const int b = blockIdx.y >> 4, h = blockIdx.y & 15;
    const int tid = threadIdx.x;
    __shared__ __align__(16) u16 t[64 * 72];
#pragma unroll
    for (int rep = 0; rep < 2; ++rep) {
        int f = rep * 256 + tid;
        int row = f >> 3, cc = (f & 7) * 8;
        *(uint4*)&t[row * 72 + cc] =
            *(const uint4*)&V[(size_t)(b * SEQ + s0 + row) * DM + h * DH + cc];
    }
    __syncthreads();
#pragma unroll
    for (int rep = 0; rep < 2; ++rep) {
        int f = rep * 256 + tid;
        int drow = f >> 3, cc = (f & 7) * 8;
        union { uint4 u; u16 s[8]; } o;
#pragma unroll
        for (int j = 0; j < 8; ++j) o.s[j] = t[(cc + j) * 72 + drow];
        *(uint4*)&Vt[(size_t)((b * NH + h) * DH + drow) * SEQ + s0 + cc] = o.u;
    }
}

// ---------------- NT GEMM (m97 structure): C[M,1024] = A[M,1024] * W[1024,1024]^T ----
// 128x128 block tile, 4 waves in 2x2, each wave 64x64 (4x4 frags), BK=64,
// global_load_lds width-16 staging (contiguous LDS, no padding).
template<bool OUTF32>
__global__ __launch_bounds__(256) void gemm128(const u16* __restrict__ Abf,
                                               const u16* __restrict__ Wbase,
                                               u16* __restrict__ outbf,
                                               float* __restrict__ outf,
                                               const int* __restrict__ pos,
                                               int ropeMask) {
    const int z  = blockIdx.z;
    const u16* Wp = Wbase + (size_t)z * (DM * DM);
    const int n0 = blockIdx.x * 128, m0 = blockIdx.y * 128;
    const int tid  = threadIdx.x;
    const int lane = tid & 63, w = tid >> 6;
    const int lm = lane & 15, quad = lane >> 4;
    const int wr = w >> 1, wc = w & 1;

    __shared__ __align__(16) u16 lsA[128 * 64];
    __shared__ __align__(16) u16 lsB[128 * 64];

    floatx4 acc[4][4];
    const floatx4 z4 = {0.f, 0.f, 0.f, 0.f};
#pragma unroll
    for (int mt = 0; mt < 4; ++mt)
#pragma unroll
        for (int nt = 0; nt < 4; ++nt) acc[mt][nt] = z4;

    for (int k0 = 0; k0 < DM; k0 += 64) {
#pragma unroll
        for (int i = 0; i < 4; ++i) {
            int f = i * 256 + tid;
            int row = f >> 3, cc = (f & 7) * 8;
            async16(&Abf[(size_t)(m0 + row) * DM + k0 + cc], &lsA[f * 8]);
            async16(&Wp[(size_t)(n0 + row) * DM + k0 + cc], &lsB[f * 8]);
        }
        __syncthreads();
#pragma unroll
        for (int ks = 0; ks < 2; ++ks) {
            bf16x8 af[4], bfr[4];
#pragma unroll
            for (int t = 0; t < 4; ++t) {
                af[t]  = *(const bf16x8*)&lsA[(wr * 64 + t * 16 + lm) * 64 + ks * 32 + quad * 8];
                bfr[t] = *(const bf16x8*)&lsB[(wc * 64 + t * 16 + lm) * 64 + ks * 32 + quad * 8];
            }
#pragma unroll
            for (int mt = 0; mt < 4; ++mt)
#pragma unroll
                for (int nt = 0; nt < 4; ++nt)
                    acc[mt][nt] = __builtin_amdgcn_mfma_f32_16x16x32_bf16(af[mt], bfr[nt], acc[mt][nt], 0, 0, 0);
        }
        __syncthreads();
    }

    const bool rope = OUTF32 ? false : (((ropeMask >> z) & 1) != 0);
    float freqs[4];
    if (rope) {
#pragma unroll
        for (int nt = 0; nt < 4; ++nt)
            freqs[nt] = __expf(-(float)((nt * 16 + lm) & 62) * (9.2103403719761836f / 64.0f));
    }

#pragma unroll
    for (int mt = 0; mt < 4; ++mt)
#pragma unroll
        for (int r = 0; r < 4; ++r) {
            int row = m0 + wr * 64 + mt * 16 + quad * 4 + r;
            float p = rope ? (float)pos[row & (SEQ - 1)] : 0.f;
#pragma unroll
            for (int nt = 0; nt < 4; ++nt) {
                int col = n0 + wc * 64 + nt * 16 + lm;
                float v  = acc[mt][nt][r];
                float pv = __shfl_xor(v, 1);
                if (rope) {
                    float sv, cv;
                    __sincosf(p * freqs[nt], &sv, &cv);
                    v = (lm & 1) ? fmaf(pv, sv, v * cv) : fmaf(v, cv, -pv * sv);
                }
                if (OUTF32) {
                    outf[(size_t)row * DM + col] = v;
                } else {
                    float hv = __shfl_xor(v, 1);
                    if (!(lm & 1)) {
                        u32 pk = (u32)f2bf(v) | ((u32)f2bf(hv) << 16);
                        *(u32*)&outbf[(size_t)z * ((size_t)MM * DM) + (size_t)row * DM + col] = pk;
                    }
                }
            }
        }
}

// ---------------- causal flash attention, q-tile 128, no-max softmax ----------------
// grid: (16 q-tiles reversed, B*H). 4 waves; wave w owns q rows [w*32, w*32+32).
__global__ __launch_bounds__(256) void attn_kernel(const u16* __restrict__ Q,
                                                   const u16* __restrict__ K,
                                                   const u16* __restrict__ Vt,
                                                   u16* __restrict__ AO) {
    const int bx = (int)gridDim.x - 1 - (int)blockIdx.x;   // heavy blocks dispatch first
    const int b  = blockIdx.y >> 4, h = blockIdx.y & 15;
    const int q0 = bx * 128;
    const int tid = threadIdx.x, w = tid >> 6, lane = tid & 63;
    const int lm = lane & 15, quad = lane >> 4;

    __shared__ __align__(16) u16 lsK[64 * 72];      // [key][dim]
    __shared__ __align__(16) u16 lsV[64 * 72];      // [dim][key] (from Vt)
    __shared__ __align__(16) u16 lsP[4][32 * 72];   // per-wave P [qrow][key]

    bf16x8 qa[2][2];
#pragma unroll
    for (int mt = 0; mt < 2; ++mt)
#pragma unroll
        for (int ks = 0; ks < 2; ++ks)
            qa[mt][ks] = *(const bf16x8*)
                &Q[(size_t)(b * SEQ + q0 + w * 32 + mt * 16 + lm) * DM + h * DH + ks * 32 + quad * 8];

    const floatx4 z4 = {0.f, 0.f, 0.f, 0.f};
    floatx4 o[2][4];
    float lsum[2][4];
#pragma unroll
    for (int mt = 0; mt < 2; ++mt)
#pragma unroll
        for (int ct = 0; ct < 4; ++ct) o[mt][ct] = z4;
#pragma unroll
    for (int mt = 0; mt < 2; ++mt)
#pragma unroll
        for (int r = 0; r < 4; ++r) lsum[mt][r] = 0.f;

    const int nkt = 2 * bx + 2;
    for (int kt = 0; kt < nkt; ++kt) {
#pragma unroll
        for (int rep = 0; rep < 2; ++rep) {
            int f = rep * 256 + tid;
            int row = f >> 3, cc = (f & 7) * 8;
            *(uint4*)&lsK[row * 72 + cc] =
                *(const uint4*)&K[(size_t)(b * SEQ + kt * 64 + row) * DM + h * DH + cc];
            *(uint4*)&lsV[row * 72 + cc] =
                *(const uint4*)&Vt[(size_t)((b * NH + h) * DH + row) * SEQ + kt * 64 + cc];
        }
        __syncthreads();

        if (kt * 64 <= q0 + w * 32 + 31) {   // wave has at least one visible key
            floatx4 s4[2][4];
#pragma unroll
            for (int mt = 0; mt < 2; ++mt)
#pragma unroll
                for (int ct = 0; ct < 4; ++ct) s4[mt][ct] = z4;
#pragma unroll
            for (int ks = 0; ks < 2; ++ks) {
#pragma unroll
                for (int ct = 0; ct < 4; ++ct) {
                    bf16x8 bb = *(const bf16x8*)&lsK[(ct * 16 + lm) * 72 + ks * 32 + quad * 8];
                    s4[0][ct] = __builtin_amdgcn_mfma_f32_16x16x32_bf16(qa[0][ks], bb, s4[0][ct], 0, 0, 0);
                    s4[1][ct] = __builtin_amdgcn_mfma_f32_16x16x32_bf16(qa[1][ks], bb, s4[1][ct], 0, 0, 0);
                }
            }

            const bool diag = (kt >= 2 * bx);
#pragma unroll
            for (int mt = 0; mt < 2; ++mt)
#pragma unroll
                for (int ct = 0; ct < 4; ++ct)
#pragma unroll
                    for (int r = 0; r < 4; ++r) {
                        float v = s4[mt][ct][r] * 0.125f;
                        if (diag) {
                            int key = kt * 64 + ct * 16 + lm;
                            int qr  = q0 + w * 32 + mt * 16 + quad * 4 + r;
                            if (key > qr) v = -1e30f;
                        }
                        float pexp = __expf(fminf(v, 60.f));
                        lsum[mt][r] += pexp;
                        s4[mt][ct][r] = pexp;
                    }

            // spill P as packed u32 pairs (even lanes store own|partner)
#pragma unroll
            for (int mt = 0; mt < 2; ++mt)
#pragma unroll
                for (int ct = 0; ct < 4; ++ct)
#pragma unroll
                    for (int r = 0; r < 4; ++r) {
                        float pexp = s4[mt][ct][r];
                        float ph   = __shfl_xor(pexp, 1);
                        if (!(lm & 1)) {
                            u32 pk = (u32)f2bf(pexp) | ((u32)f2bf(ph) << 16);
                            *(u32*)&lsP[w][(mt * 16 + quad * 4 + r) * 72 + ct * 16 + lm] = pk;
                        }
                    }

            // O += P * V
#pragma unroll
            for (int ks = 0; ks < 2; ++ks) {
                bf16x8 ap0 = *(const bf16x8*)&lsP[w][(lm) * 72 + ks * 32 + quad * 8];
                bf16x8 ap1 = *(const bf16x8*)&lsP[w][(16 + lm) * 72 + ks * 32 + quad * 8];
#pragma unroll
                for (int ct = 0; ct < 4; ++ct) {
                    bf16x8 bv = *(const bf16x8*)&lsV[(ct * 16 + lm) * 72 + ks * 32 + quad * 8];
                    o[0][ct] = __builtin_amdgcn_mfma_f32_16x16x32_bf16(ap0, bv, o[0][ct], 0, 0, 0);
                    o[1][ct] = __builtin_amdgcn_mfma_f32_16x16x32_bf16(ap1, bv, o[1][ct], 0, 0, 0);
                }
            }
        }
        __syncthreads();
    }

    // single final reduction of row sums across the 16 lanes holding each row
#pragma unroll
    for (int mt = 0; mt < 2; ++mt)
#pragma unroll
        for (int r = 0; r < 4; ++r) {
            float s = lsum[mt][r];
#pragma unroll
            for (int off = 1; off < 16; off <<= 1) s += __shfl_xor(s, off);
            lsum[mt][r] = s;
        }

#pragma unroll
    for (int mt = 0; mt < 2; ++mt)
#pragma unroll
        for (int ct = 0; ct < 4; ++ct)
#pragma unroll
            for (int r = 0; r < 4; ++r) {
                float v  = o[mt][ct][r] / lsum[mt][r];
                float hv = __shfl_xor(v, 1);
                if (!(lm & 1)) {
                    u32 pk = (u32)f2bf(v) | ((u32)f2bf(hv) << 16);
                    *(u32*)&AO[(size_t)(b * SEQ + q0 + w * 32 + mt * 16 + quad * 4 + r) * DM
                               + h * DH + ct * 16 + lm] = pk;
                }
            }
}

extern "C" void kernel_launch(void* const* d_in, const int* in_sizes, int n_in,
                              void* d_out, int out_size, void* d_ws, size_t ws_size,
                              hipStream_t stream) {
    const float* x   = (const float*)d_in[0];
    const int*   pos = (const int*)d_in[1];
    const float* Wsrc[4] = {(const float*)d_in[2], (const float*)d_in[3],
                            (const float*)d_in[4], (const float*)d_in[5]};
    float* out = (float*)d_out;

    u16* ws = (u16*)d_ws;
    const size_t MD = (size_t)MM * DM;   // 4Mi elements
    const size_t DD = (size_t)DM * DM;   // 1Mi elements
    u16* Xbf = ws;                        // [4096,1024]; dead after QKV -> reused as Vt
    u16* Wbf = ws + MD;                   // 4 weights contiguous (q,k,v,o)
    u16* Qbf = ws + MD + 4 * DD;
    u16* Kbf = Qbf + MD;
    u16* Vbf = Kbf + MD;                  // dead after transpose -> reused as AO
    u16* Vt   = Xbf;
    u16* AObf = Vbf;

    cvt_kernel<<<(int)(MD / 4 / 256), 256, 0, stream>>>(x, Xbf, (int)(MD / 4));
    for (int i = 0; i < 4; ++i)
        cvt_kernel<<<(int)(DD / 4 / 256), 256, 0, stream>>>(Wsrc[i], Wbf + i * DD, (int)(DD / 4));

    // Q/K/V projections + fused RoPE on Q,K
    gemm128<false><<<dim3(8, 32, 3), 256, 0, stream>>>(Xbf, Wbf, Qbf, nullptr, pos, 0x3);

    // V -> Vt[b,h,d,s]
    transpose_v<<<dim3(SEQ / 64, 2 * NH), 256, 0, stream>>>(Vbf, Vt);

    // causal flash attention (128-row q-tiles, reversed dispatch)
    attn_kernel<<<dim3(16, 2 * NH), 256, 0, stream>>>(Qbf, Kbf, Vt, AObf);

    // output projection -> fp32 d_out
    gemm128<true><<<dim3(8, 32, 1), 256, 0, stream>>>(AObf, Wbf + 3 * DD, nullptr, out, nullptr, 0);
}

// Round 3
// 273.677 us; speedup vs baseline: 1.3068x; 1.1483x over previous
//
#include <hip/hip_runtime.h>
#include <math.h>

typedef unsigned short u16;
typedef unsigned int   u32;
typedef __attribute__((ext_vector_type(8))) short bf16x8;
typedef __attribute__((ext_vector_type(4))) float floatx4;

// B=2, S=2048, D=1024, H=16, Dh=64, M=B*S=4096
#define SEQ 2048
#define DM  1024
#define NH  16
#define DH  64
#define MM  4096
#define QSCALE 0.18033688011112042f   // 0.125 * log2(e), folded into Q

__device__ __forceinline__ u16 f2bf(float f) {
    u32 u = __builtin_bit_cast(u32, f);
    u += 0x7fffu + ((u >> 16) & 1u);
    return (u16)(u >> 16);
}

__device__ __forceinline__ void async16(const u16* g, u16* l) {
    __builtin_amdgcn_global_load_lds(
        (const __attribute__((address_space(1))) void*)g,
        (__attribute__((address_space(3))) void*)l, 16, 0, 0);
}

// ---------------- fp32 -> bf16 converts ----------------
__global__ void cvt_kernel(const float* __restrict__ src, u16* __restrict__ dst, int n4) {
    int i = blockIdx.x * 256 + threadIdx.x;
    if (i >= n4) return;
    float4 f = ((const float4*)src)[i];
    uint2 o;
    o.x = (u32)f2bf(f.x) | ((u32)f2bf(f.y) << 16);
    o.y = (u32)f2bf(f.z) | ((u32)f2bf(f.w) << 16);
    ((uint2*)dst)[i] = o;
}

__global__ void cvt4_kernel(const float* __restrict__ w0, const float* __restrict__ w1,
                            const float* __restrict__ w2, const float* __restrict__ w3,
                            u16* __restrict__ dst, int n4) {
    int i = blockIdx.x * 256 + threadIdx.x;
    if (i >= n4) return;
    const float* src = (blockIdx.y == 0) ? w0 : (blockIdx.y == 1) ? w1 : (blockIdx.y == 2) ? w2 : w3;
    float4 f = ((const float4*)src)[i];
    uint2 o;
    o.x = (u32)f2bf(f.x) | ((u32)f2bf(f.y) << 16);
    o.y = (u32)f2bf(f.z) | ((u32)f2bf(f.w) << 16);
    ((uint2*)(dst + (size_t)blockIdx.y * DM * DM))[i] = o;
}

// ---------------- V transpose: V[b,s,h*64+d] -> Vt[(b*16+h)*64+d][s] ----------------
__global__ __launch_bounds__(256) void transpose_v(const u16* __restrict__ V, u16* __restrict__ Vt) {
    const int s0 = blockIdx.x * 64;
    const int b = blockIdx.y >> 4, h = blockIdx.y & 15;
    const int tid = threadIdx.x;
    __shared__ __align__(16) u16 t[64 * 72];
#pragma unroll
    for (int rep = 0; rep < 2; ++rep) {
        int f = rep * 256 + tid;
        int row = f >> 3, cc = (f & 7) * 8;
        *(uint4*)&t[row * 72 + cc] =
            *(const uint4*)&V[(size_t)(b * SEQ + s0 + row) * DM + h * DH + cc];
    }
    __syncthreads();
#pragma unroll
    for (int rep = 0; rep < 2; ++rep) {
        int f = rep * 256 + tid;
        int drow = f >> 3, cc = (f & 7) * 8;
        union { uint4 u; u16 s[8]; } o;
#pragma unroll
        for (int j = 0; j < 8; ++j) o.s[j] = t[(cc + j) * 72 + drow];
        *(uint4*)&Vt[(size_t)((b * NH + h) * DH + drow) * SEQ + s0 + cc] = o.u;
    }
}

// ---------------- NT GEMM: C[M,1024] = A[M,1024] * W[1024,1024]^T ----------------
// 128x128 tile, 4 waves 2x2, each wave 64x64 (4x4 frags), BK=64,
// async staging with XOR column-block swizzle (conflict-free b128 reads, no pad).
template<bool OUTF32>
__global__ __launch_bounds__(256) void gemm128(const u16* __restrict__ Abf,
                                               const u16* __restrict__ Wbase,
                                               u16* __restrict__ outbf,
                                               float* __restrict__ outf,
                                               const int* __restrict__ pos,
                                               int ropeMask) {
    const int z  = blockIdx.z;
    const u16* Wp = Wbase + (size_t)z * (DM * DM);
    const int n0 = blockIdx.x * 128, m0 = blockIdx.y * 128;
    const int tid  = threadIdx.x;
    const int lane = tid & 63, w = tid >> 6;
    const int lm = lane & 15, quad = lane >> 4;
    const int wr = w >> 1, wc = w & 1;

    __shared__ __align__(16) u16 lsA[128 * 64];
    __shared__ __align__(16) u16 lsB[128 * 64];

    floatx4 acc[4][4];
    const floatx4 z4 = {0.f, 0.f, 0.f, 0.f};
#pragma unroll
    for (int mt = 0; mt < 4; ++mt)
#pragma unroll
        for (int nt = 0; nt < 4; ++nt) acc[mt][nt] = z4;

    const int sw = lm & 7;   // row&7 for all fragment rows this lane touches

    for (int k0 = 0; k0 < DM; k0 += 64) {
#pragma unroll
        for (int i = 0; i < 4; ++i) {
            int f = i * 256 + tid;
            int row = f >> 3, cb = f & 7;
            int scb = cb ^ (row & 7);
            async16(&Abf[(size_t)(m0 + row) * DM + k0 + scb * 8], &lsA[f * 8]);
            async16(&Wp[(size_t)(n0 + row) * DM + k0 + scb * 8], &lsB[f * 8]);
        }
        __syncthreads();
#pragma unroll
        for (int ks = 0; ks < 2; ++ks) {
            const int cbl = ((ks * 4 + quad) ^ sw) * 8;
            bf16x8 af[4], bfr[4];
#pragma unroll
            for (int t = 0; t < 4; ++t) {
                af[t]  = *(const bf16x8*)&lsA[(wr * 64 + t * 16 + lm) * 64 + cbl];
                bfr[t] = *(const bf16x8*)&lsB[(wc * 64 + t * 16 + lm) * 64 + cbl];
            }
#pragma unroll
            for (int mt = 0; mt < 4; ++mt)
#pragma unroll
                for (int nt = 0; nt < 4; ++nt)
                    acc[mt][nt] = __builtin_amdgcn_mfma_f32_16x16x32_bf16(af[mt], bfr[nt], acc[mt][nt], 0, 0, 0);
        }
        __syncthreads();
    }

    const bool rope = OUTF32 ? false : (((ropeMask >> z) & 1) != 0);
    const float osc = (!OUTF32 && z == 0) ? QSCALE : 1.0f;
    float freqs[4];
    if (rope) {
#pragma unroll
        for (int nt = 0; nt < 4; ++nt)
            freqs[nt] = __expf(-(float)((nt * 16 + lm) & 62) * (9.2103403719761836f / 64.0f));
    }

#pragma unroll
    for (int mt = 0; mt < 4; ++mt)
#pragma unroll
        for (int r = 0; r < 4; ++r) {
            int row = m0 + wr * 64 + mt * 16 + quad * 4 + r;
            float p = rope ? (float)pos[row & (SEQ - 1)] : 0.f;
#pragma unroll
            for (int nt = 0; nt < 4; ++nt) {
                int col = n0 + wc * 64 + nt * 16 + lm;
                float v  = acc[mt][nt][r];
                float pv = __shfl_xor(v, 1);
                if (rope) {
                    float sv, cv;
                    __sincosf(p * freqs[nt], &sv, &cv);
                    v = (lm & 1) ? fmaf(pv, sv, v * cv) : fmaf(v, cv, -pv * sv);
                }
                v *= osc;
                if (OUTF32) {
                    outf[(size_t)row * DM + col] = v;
                } else {
                    float hv = __shfl_xor(v, 1);
                    if (!(lm & 1)) {
                        u32 pk = (u32)f2bf(v) | ((u32)f2bf(hv) << 16);
                        *(u32*)&outbf[(size_t)z * ((size_t)MM * DM) + (size_t)row * DM + col] = pk;
                    }
                }
            }
        }
}

// ---------------- causal flash attention ----------------
// q-tile 128, 8 waves x 16 rows; k-tile 64; no-max softmax (scale pre-folded, exp2);
// async swizzled K/V staging; grid (16 reversed, B*H).
__global__ __launch_bounds__(512) void attn_kernel(const u16* __restrict__ Q,
                                                   const u16* __restrict__ K,
                                                   const u16* __restrict__ Vt,
                                                   u16* __restrict__ AO) {
    const int bx = (int)gridDim.x - 1 - (int)blockIdx.x;   // heavy blocks first
    const int b  = blockIdx.y >> 4, h = blockIdx.y & 15;
    const int q0 = bx * 128;
    const int tid = threadIdx.x, w = tid >> 6, lane = tid & 63;
    const int lm = lane & 15, quad = lane >> 4;
    const int sw = lm & 7;

    __shared__ __align__(16) u16 lsK[64 * 64];      // [key][dim], col-swizzled
    __shared__ __align__(16) u16 lsV[64 * 64];      // [dim][key], col-swizzled
    __shared__ __align__(16) u16 lsP[8][16 * 72];   // per-wave P [qrow][key]

    bf16x8 qa[2];
#pragma unroll
    for (int ks = 0; ks < 2; ++ks)
        qa[ks] = *(const bf16x8*)
            &Q[(size_t)(b * SEQ + q0 + w * 16 + lm) * DM + h * DH + ks * 32 + quad * 8];

    const floatx4 z4 = {0.f, 0.f, 0.f, 0.f};
    floatx4 o[4];
    float lsum[4];
#pragma unroll
    for (int ct = 0; ct < 4; ++ct) o[ct] = z4;
#pragma unroll
    for (int r = 0; r < 4; ++r) lsum[r] = 0.f;

    // staging addresses for this thread (row/colblock with XOR swizzle)
    const int srow = tid >> 3, scb = (tid & 7) ^ (srow & 7);

    const int nkt = 2 * bx + 2;
    for (int kt = 0; kt < nkt; ++kt) {
        async16(&K[(size_t)(b * SEQ + kt * 64 + srow) * DM + h * DH + scb * 8], &lsK[tid * 8]);
        async16(&Vt[(size_t)((b * NH + h) * DH + srow) * SEQ + kt * 64 + scb * 8], &lsV[tid * 8]);
        __syncthreads();

        if (kt * 64 <= q0 + w * 16 + 15) {   // wave has >=1 visible key
            floatx4 s4[4];
#pragma unroll
            for (int ct = 0; ct < 4; ++ct) s4[ct] = z4;
#pragma unroll
            for (int ks = 0; ks < 2; ++ks) {
                const int cbl = ((ks * 4 + quad) ^ sw) * 8;
#pragma unroll
                for (int ct = 0; ct < 4; ++ct) {
                    bf16x8 bb = *(const bf16x8*)&lsK[(ct * 16 + lm) * 64 + cbl];
                    s4[ct] = __builtin_amdgcn_mfma_f32_16x16x32_bf16(qa[ks], bb, s4[ct], 0, 0, 0);
                }
            }

            const bool diag = (kt * 64 + 63 > q0 + w * 16);
#pragma unroll
            for (int ct = 0; ct < 4; ++ct)
#pragma unroll
                for (int r = 0; r < 4; ++r) {
                    float v = s4[ct][r];
                    if (diag) {
                        int key = kt * 64 + ct * 16 + lm;
                        int qr  = q0 + w * 16 + quad * 4 + r;
                        if (key > qr) v = -1e30f;
                    }
                    float pexp = exp2f(fminf(v, 80.f));
                    lsum[r] += pexp;
                    float ph = __shfl_xor(pexp, 1);
                    if (!(lm & 1)) {
                        u32 pk = (u32)f2bf(pexp) | ((u32)f2bf(ph) << 16);
                        *(u32*)&lsP[w][(quad * 4 + r) * 72 + ct * 16 + lm] = pk;
                    }
                }

            // O += P * V
#pragma unroll
            for (int ks = 0; ks < 2; ++ks) {
                bf16x8 ap = *(const bf16x8*)&lsP[w][lm * 72 + ks * 32 + quad * 8];
                const int cbl = ((ks * 4 + quad) ^ sw) * 8;
#pragma unroll
                for (int ct = 0; ct < 4; ++ct) {
                    bf16x8 bv = *(const bf16x8*)&lsV[(ct * 16 + lm) * 64 + cbl];
                    o[ct] = __builtin_amdgcn_mfma_f32_16x16x32_bf16(ap, bv, o[ct], 0, 0, 0);
                }
            }
        }
        __syncthreads();
    }

    // final row-sum reduction across the 16 lanes holding each row
#pragma unroll
    for (int r = 0; r < 4; ++r) {
        float s = lsum[r];
#pragma unroll
        for (int off = 1; off < 16; off <<= 1) s += __shfl_xor(s, off);
        lsum[r] = s;
    }

#pragma unroll
    for (int ct = 0; ct < 4; ++ct)
#pragma unroll
        for (int r = 0; r < 4; ++r) {
            float v  = o[ct][r] / lsum[r];
            float hv = __shfl_xor(v, 1);
            if (!(lm & 1)) {
                u32 pk = (u32)f2bf(v) | ((u32)f2bf(hv) << 16);
                *(u32*)&AO[(size_t)(b * SEQ + q0 + w * 16 + quad * 4 + r) * DM
                           + h * DH + ct * 16 + lm] = pk;
            }
        }
}

extern "C" void kernel_launch(void* const* d_in, const int* in_sizes, int n_in,
                              void* d_out, int out_size, void* d_ws, size_t ws_size,
                              hipStream_t stream) {
    const float* x   = (const float*)d_in[0];
    const int*   pos = (const int*)d_in[1];
    float* out = (float*)d_out;

    u16* ws = (u16*)d_ws;
    const size_t MD = (size_t)MM * DM;
    const size_t DD = (size_t)DM * DM;
    u16* Xbf = ws;                        // dead after QKV -> reused as Vt
    u16* Wbf = ws + MD;
    u16* Qbf = ws + MD + 4 * DD;
    u16* Kbf = Qbf + MD;
    u16* Vbf = Kbf + MD;                  // dead after transpose -> reused as AO
    u16* Vt   = Xbf;
    u16* AObf = Vbf;

    cvt_kernel<<<(int)(MD / 4 / 256), 256, 0, stream>>>(x, Xbf, (int)(MD / 4));
    cvt4_kernel<<<dim3((int)(DD / 4 / 256), 4), 256, 0, stream>>>(
        (const float*)d_in[2], (const float*)d_in[3], (const float*)d_in[4], (const float*)d_in[5],
        Wbf, (int)(DD / 4));

    // Q/K/V projections + fused RoPE on Q,K; softmax scale folded into Q
    gemm128<false><<<dim3(8, 32, 3), 256, 0, stream>>>(Xbf, Wbf, Qbf, nullptr, pos, 0x3);

    // V -> Vt[b,h,d,s]
    transpose_v<<<dim3(SEQ / 64, 2 * NH), 256, 0, stream>>>(Vbf, Vt);

    // causal flash attention
    attn_kernel<<<dim3(16, 2 * NH), 512, 0, stream>>>(Qbf, Kbf, Vt, AObf);

    // output projection -> fp32 d_out
    gemm128<true><<<dim3(8, 32, 1), 256, 0, stream>>>(AObf, Wbf + 3 * DD, nullptr, out, nullptr, 0);
}

// Round 5
// 231.880 us; speedup vs baseline: 1.5424x; 1.1803x over previous
//
#include <hip/hip_runtime.h>
#include <math.h>

typedef unsigned short u16;
typedef unsigned int   u32;
typedef __attribute__((ext_vector_type(8))) short bf16x8;
typedef __attribute__((ext_vector_type(4))) float floatx4;
typedef __attribute__((ext_vector_type(4))) _Float16 halfx4;
typedef __attribute__((ext_vector_type(2))) unsigned int uintx2;

// B=2, S=2048, D=1024, H=16, Dh=64, M=B*S=4096
#define SEQ 2048
#define DM  1024
#define NH  16
#define DH  64
#define MM  4096
#define QSCALE 0.18033688011112042f   // 0.125 * log2(e), folded into Q

__device__ __forceinline__ u16 f2bf(float f) {
    u32 u = __builtin_bit_cast(u32, f);
    u += 0x7fffu + ((u >> 16) & 1u);
    return (u16)(u >> 16);
}

__device__ __forceinline__ void async16(const void* g, void* l) {
    __builtin_amdgcn_global_load_lds(
        (const __attribute__((address_space(1))) void*)g,
        (__attribute__((address_space(3))) void*)l, 16, 0, 0);
}

// ---------------- fp32 -> bf16 converts ----------------
__global__ void cvt_kernel(const float* __restrict__ src, u16* __restrict__ dst, int n4) {
    int i = blockIdx.x * 256 + threadIdx.x;
    if (i >= n4) return;
    float4 f = ((const float4*)src)[i];
    uint2 o;
    o.x = (u32)f2bf(f.x) | ((u32)f2bf(f.y) << 16);
    o.y = (u32)f2bf(f.z) | ((u32)f2bf(f.w) << 16);
    ((uint2*)dst)[i] = o;
}

__global__ void cvt4_kernel(const float* __restrict__ w0, const float* __restrict__ w1,
                            const float* __restrict__ w2, const float* __restrict__ w3,
                            u16* __restrict__ dst, int n4) {
    int i = blockIdx.x * 256 + threadIdx.x;
    if (i >= n4) return;
    const float* src = (blockIdx.y == 0) ? w0 : (blockIdx.y == 1) ? w1 : (blockIdx.y == 2) ? w2 : w3;
    float4 f = ((const float4*)src)[i];
    uint2 o;
    o.x = (u32)f2bf(f.x) | ((u32)f2bf(f.y) << 16);
    o.y = (u32)f2bf(f.z) | ((u32)f2bf(f.w) << 16);
    ((uint2*)(dst + (size_t)blockIdx.y * DM * DM))[i] = o;
}

// ---------------- RoPE table: tab[pos][d2] = (cos, sin), 2048 x 32 ----------------
__global__ void rope_tab_kernel(const int* __restrict__ pos, float2* __restrict__ tab) {
    int i = blockIdx.x * 256 + threadIdx.x;   // 65536
    int p = i >> 5, d2 = i & 31;
    float freq = __expf(-(float)d2 * (9.2103403719761836f / 32.0f));
    float sv, cv;
    sincosf((float)pos[p] * freq, &sv, &cv);
    tab[i] = make_float2(cv, sv);
}

// ---------------- V transpose + f16 convert: V[b,s,h*64+d] -> Vt[(b*16+h)*64+d][s] ----
__global__ __launch_bounds__(256) void transpose_v(const u16* __restrict__ V, _Float16* __restrict__ Vt) {
    const int s0 = blockIdx.x * 64;
    const int b = blockIdx.y >> 4, h = blockIdx.y & 15;
    const int tid = threadIdx.x;
    __shared__ __align__(16) u16 t[64 * 72];
#pragma unroll
    for (int rep = 0; rep < 2; ++rep) {
        int f = rep * 256 + tid;
        int row = f >> 3, cc = (f & 7) * 8;
        *(uint4*)&t[row * 72 + cc] =
            *(const uint4*)&V[(size_t)(b * SEQ + s0 + row) * DM + h * DH + cc];
    }
    __syncthreads();
#pragma unroll
    for (int rep = 0; rep < 2; ++rep) {
        int f = rep * 256 + tid;
        int drow = f >> 3, cc = (f & 7) * 8;
        _Float16 o[8];
#pragma unroll
        for (int j = 0; j < 8; ++j) {
            u32 bits = (u32)t[(cc + j) * 72 + drow] << 16;
            o[j] = (_Float16)__builtin_bit_cast(float, bits);
        }
        *(uint4*)&Vt[(size_t)((b * NH + h) * DH + drow) * SEQ + s0 + cc] = *(uint4*)o;
    }
}

// ---------------- NT GEMM: C[M,1024] = A[M,1024] * W[1024,1024]^T ----------------
// 128x128 tile, grid (32 m, 8 n, z): same-A blocks share XCD. RoPE via table.
template<bool OUTF32>
__global__ __launch_bounds__(256) void gemm128(const u16* __restrict__ Abf,
                                               const u16* __restrict__ Wbase,
                                               u16* __restrict__ outbf,
                                               float* __restrict__ outf,
                                               const float2* __restrict__ ropetab,
                                               int ropeMask) {
    const int z  = blockIdx.z;
    const u16* Wp = Wbase + (size_t)z * (DM * DM);
    const int m0 = blockIdx.x * 128, n0 = blockIdx.y * 128;
    const int tid  = threadIdx.x;
    const int lane = tid & 63, w = tid >> 6;
    const int lm = lane & 15, quad = lane >> 4;
    const int wr = w >> 1, wc = w & 1;

    __shared__ __align__(16) u16 lsA[128 * 64];
    __shared__ __align__(16) u16 lsB[128 * 64];

    floatx4 acc[4][4];
    const floatx4 z4 = {0.f, 0.f, 0.f, 0.f};
#pragma unroll
    for (int mt = 0; mt < 4; ++mt)
#pragma unroll
        for (int nt = 0; nt < 4; ++nt) acc[mt][nt] = z4;

    const int sw = lm & 7;

    for (int k0 = 0; k0 < DM; k0 += 64) {
#pragma unroll
        for (int i = 0; i < 4; ++i) {
            int f = i * 256 + tid;
            int row = f >> 3, cb = f & 7;
            int scb = cb ^ (row & 7);
            async16(&Abf[(size_t)(m0 + row) * DM + k0 + scb * 8], &lsA[f * 8]);
            async16(&Wp[(size_t)(n0 + row) * DM + k0 + scb * 8], &lsB[f * 8]);
        }
        __syncthreads();
#pragma unroll
        for (int ks = 0; ks < 2; ++ks) {
            const int cbl = ((ks * 4 + quad) ^ sw) * 8;
            bf16x8 af[4], bfr[4];
#pragma unroll
            for (int t = 0; t < 4; ++t) {
                af[t]  = *(const bf16x8*)&lsA[(wr * 64 + t * 16 + lm) * 64 + cbl];
                bfr[t] = *(const bf16x8*)&lsB[(wc * 64 + t * 16 + lm) * 64 + cbl];
            }
#pragma unroll
            for (int mt = 0; mt < 4; ++mt)
#pragma unroll
                for (int nt = 0; nt < 4; ++nt)
                    acc[mt][nt] = __builtin_amdgcn_mfma_f32_16x16x32_bf16(af[mt], bfr[nt], acc[mt][nt], 0, 0, 0);
        }
        __syncthreads();
    }

    const bool rope = OUTF32 ? false : (((ropeMask >> z) & 1) != 0);
    const float osc = (!OUTF32 && z == 0) ? QSCALE : 1.0f;

#pragma unroll
    for (int mt = 0; mt < 4; ++mt)
#pragma unroll
        for (int r = 0; r < 4; ++r) {
            int row = m0 + wr * 64 + mt * 16 + quad * 4 + r;
#pragma unroll
            for (int nt = 0; nt < 4; ++nt) {
                int col = n0 + wc * 64 + nt * 16 + lm;
                float v  = acc[mt][nt][r];
                if (rope) {
                    float pv = __shfl_xor(v, 1);
                    float2 cs = ropetab[(row & (SEQ - 1)) * 32 + (((nt * 16 + lm) >> 1) & 31)];
                    v = (lm & 1) ? fmaf(pv, cs.y, v * cs.x) : fmaf(v, cs.x, -pv * cs.y);
                }
                v *= osc;
                if (OUTF32) {
                    outf[(size_t)row * DM + col] = v;
                } else {
                    float hv = __shfl_xor(v, 1);
                    if (!(lm & 1)) {
                        u32 pk = (u32)f2bf(v) | ((u32)f2bf(hv) << 16);
                        *(u32*)&outbf[(size_t)z * ((size_t)MM * DM) + (size_t)row * DM + col] = pk;
                    }
                }
            }
        }
}

// ---------------- causal flash attention, S^T formulation ----------------
// q-tile 128, 8 waves x 16 q-rows; k-tile 128; P^T kept in registers (C-layout ==
// B-frag of 16x16x16 MFMA); V^T in f16. Balanced block map: CU pairs sum to 17 iters.
__global__ __launch_bounds__(512) void attn_kernel(const u16* __restrict__ Q,
                                                   const u16* __restrict__ K,
                                                   const _Float16* __restrict__ Vt,
                                                   u16* __restrict__ AO) {
    const int u  = blockIdx.x;
    const int qt = (u < 256) ? (15 - (u >> 5)) : ((u >> 5) - 8);
    const int bh = u & 31;
    const int b  = bh >> 4, h = bh & 15;
    const int q0 = qt * 128;
    const int tid = threadIdx.x, w = tid >> 6, lane = tid & 63;
    const int lm = lane & 15, quad = lane >> 4;

    __shared__ __align__(16) u16      lsK[128 * 64];   // [key][dim], col-swizzled (8x16B blocks ^ row&7)
    __shared__ __align__(16) _Float16 lsV[64 * 128];   // [dim][key], 16B-block swizzle ^ (d>>1)&7

    // Q B-frags (x32): q = lm, d = ks*32 + quad*8..+8
    bf16x8 qb[2];
#pragma unroll
    for (int ks = 0; ks < 2; ++ks)
        qb[ks] = *(const bf16x8*)
            &Q[(size_t)(b * SEQ + q0 + w * 16 + lm) * DM + h * DH + ks * 32 + quad * 8];

    const floatx4 z4 = {0.f, 0.f, 0.f, 0.f};
    floatx4 o[4];                 // O^T[d][q]: d = dt*16+quad*4+r, q = lm
#pragma unroll
    for (int dt = 0; dt < 4; ++dt) o[dt] = z4;
    float lsum = 0.f;

    const int qloc = w * 16 + lm;  // q row within tile for this lane

    for (int kt = 0; kt <= qt; ++kt) {
        // stage K (128x64 bf16) and V^T (64x128 f16), 4 async16 per thread
#pragma unroll
        for (int rep = 0; rep < 2; ++rep) {
            int f = rep * 512 + tid;
            int krow = f >> 3, kcb = (f & 7) ^ (krow & 7);
            async16(&K[(size_t)(b * SEQ + kt * 128 + krow) * DM + h * DH + kcb * 8], &lsK[f * 8]);
            int d = f >> 4, gbs = (f & 15) ^ ((d >> 1) & 7);
            async16(&Vt[(size_t)(bh * DH + d) * SEQ + kt * 128 + gbs * 8], &lsV[f * 8]);
        }
        __syncthreads();

        // S^T[s][q] = K · Q^T : A = K-frag, B = Q-frag
        floatx4 s4[8];
#pragma unroll
        for (int st = 0; st < 8; ++st) s4[st] = z4;
#pragma unroll
        for (int ks = 0; ks < 2; ++ks) {
            const int cbl = ((ks * 4 + quad) ^ (lm & 7)) * 8;
#pragma unroll
            for (int st = 0; st < 8; ++st) {
                bf16x8 ka = *(const bf16x8*)&lsK[(st * 16 + lm) * 64 + cbl];
                s4[st] = __builtin_amdgcn_mfma_f32_16x16x32_bf16(ka, qb[ks], s4[st], 0, 0, 0);
            }
        }

        // softmax (no-max; scale pre-folded into Q) + pack P^T to f16 B-frags
        halfx4 pb[8];
        const bool diag = (kt == qt);
#pragma unroll
        for (int st = 0; st < 8; ++st) {
#pragma unroll
            for (int r = 0; r < 4; ++r) {
                float v = s4[st][r];
                if (diag) {
                    int keyloc = st * 16 + quad * 4 + r;
                    if (keyloc > qloc) v = -1e30f;
                }
                v = exp2f(v);
                lsum += v;
                s4[st][r] = v;
            }
            uintx2 pk2;
            pk2.x = __builtin_bit_cast(u32, __builtin_amdgcn_cvt_pkrtz(s4[st][0], s4[st][1]));
            pk2.y = __builtin_bit_cast(u32, __builtin_amdgcn_cvt_pkrtz(s4[st][2], s4[st][3]));
            pb[st] = __builtin_bit_cast(halfx4, pk2);
        }

        // O^T += V^T · P^T  (x16 f16 MFMA; acc regs of S^T are the B operand)
#pragma unroll
        for (int st = 0; st < 8; ++st) {
#pragma unroll
            for (int dt = 0; dt < 4; ++dt) {
                int drow = dt * 16 + lm;
                int sbs = (st * 2 + (quad >> 1)) ^ ((drow >> 1) & 7);
                halfx4 va = *(const halfx4*)&lsV[drow * 128 + sbs * 8 + (quad & 1) * 4];
                o[dt] = __builtin_amdgcn_mfma_f32_16x16x16f16(va, pb[st], o[dt], 0, 0, 0);
            }
        }
        __syncthreads();
    }

    // reduce row sum across the 4 quads holding q = lm
    lsum += __shfl_xor(lsum, 16);
    lsum += __shfl_xor(lsum, 32);
    float rl = 1.0f / lsum;

    // store O (bf16): row q = q0 + w*16 + lm, cols h*64 + dt*16 + quad*4 .. +3
#pragma unroll
    for (int dt = 0; dt < 4; ++dt) {
        uint2 pk;
        pk.x = (u32)f2bf(o[dt][0] * rl) | ((u32)f2bf(o[dt][1] * rl) << 16);
        pk.y = (u32)f2bf(o[dt][2] * rl) | ((u32)f2bf(o[dt][3] * rl) << 16);
        *(uint2*)&AO[(size_t)(b * SEQ + q0 + w * 16 + lm) * DM + h * DH + dt * 16 + quad * 4] = pk;
    }
}

extern "C" void kernel_launch(void* const* d_in, const int* in_sizes, int n_in,
                              void* d_out, int out_size, void* d_ws, size_t ws_size,
                              hipStream_t stream) {
    const float* x   = (const float*)d_in[0];
    const int*   pos = (const int*)d_in[1];
    float* out = (float*)d_out;

    u16* ws = (u16*)d_ws;
    const size_t MD = (size_t)MM * DM;
    const size_t DD = (size_t)DM * DM;
    u16* Xbf = ws;                        // dead after QKV -> reused as Vt (f16, same bytes)
    u16* Wbf = ws + MD;
    u16* Qbf = ws + MD + 4 * DD;
    u16* Kbf = Qbf + MD;
    u16* Vbf = Kbf + MD;                  // dead after transpose -> reused as AO
    float2* ropetab = (float2*)(ws + 4 * MD + 4 * DD);   // 2048*32*8B = 512 KB
    _Float16* Vt = (_Float16*)Xbf;
    u16* AObf = Vbf;

    cvt_kernel<<<(int)(MD / 4 / 256), 256, 0, stream>>>(x, Xbf, (int)(MD / 4));
    cvt4_kernel<<<dim3((int)(DD / 4 / 256), 4), 256, 0, stream>>>(
        (const float*)d_in[2], (const float*)d_in[3], (const float*)d_in[4], (const float*)d_in[5],
        Wbf, (int)(DD / 4));
    rope_tab_kernel<<<SEQ * 32 / 256, 256, 0, stream>>>(pos, ropetab);

    // Q/K/V projections + fused RoPE on Q,K; softmax scale folded into Q
    gemm128<false><<<dim3(32, 8, 3), 256, 0, stream>>>(Xbf, Wbf, Qbf, nullptr, ropetab, 0x3);

    // V -> Vt[b,h,d,s] in f16
    transpose_v<<<dim3(SEQ / 64, 2 * NH), 256, 0, stream>>>(Vbf, Vt);

    // causal flash attention
    attn_kernel<<<dim3(512), 512, 0, stream>>>(Qbf, Kbf, Vt, AObf);

    // output projection -> fp32 d_out
    gemm128<true><<<dim3(32, 8, 1), 256, 0, stream>>>(AObf, Wbf + 3 * DD, nullptr, out, nullptr, 0);
}